// Round 14
// baseline (177.695 us; speedup 1.0000x reference)
//
#include <hip/hip_runtime.h>
#include <hip/hip_bf16.h>

#define NH 12
#define HD 64
#define NB 4
#define SEQ 2048
#define NP 768
#define LOG2E 1.44269504f
#define MASK_L2 14426.9504f   // 10000 * log2(e)

typedef __bf16 bf16x8 __attribute__((ext_vector_type(8)));
typedef __bf16 bf16x2 __attribute__((ext_vector_type(2)));
typedef float f32x2 __attribute__((ext_vector_type(2)));
typedef float f32x4 __attribute__((ext_vector_type(4)));
typedef float f32x16 __attribute__((ext_vector_type(16)));
typedef unsigned u32x4 __attribute__((ext_vector_type(4)));

static __device__ __forceinline__ bf16x8 load_bf16x8(const __bf16* p) {
    return *reinterpret_cast<const bf16x8*>(p);
}
static __device__ __forceinline__ float hw_exp2(float x) {
    return __builtin_amdgcn_exp2f(x);
}
// packed f32x2 -> bf16x2 (backend can select v_cvt_pk_bf16_f32 on gfx950)
static __device__ __forceinline__ unsigned cvtpk2(float lo, float hi) {
    f32x2 t; t[0] = lo; t[1] = hi;
    return __builtin_bit_cast(unsigned, __builtin_convertvector(t, bf16x2));
}

// ---------------------------------------------------------------------------
// Kernel 1 v13: QKV projection. grid (128, 2): each block does 18 of the 36
// (proj,head) tiles -> hidden is re-read 2x instead of 6x (150->50 MB).
// Vf in SIGMA-PERMUTED key order sigma(8*hi+j) = (j&3)+8*(j>>2)+4*hi.
// ---------------------------------------------------------------------------
__global__ __launch_bounds__(256) void qkv_kernel(
    const float* __restrict__ hidden,
    const float* __restrict__ Wq, const float* __restrict__ Wk,
    const float* __restrict__ Wv,
    const float* __restrict__ bq, const float* __restrict__ bk,
    const float* __restrict__ bv,
    __bf16* __restrict__ Qw, __bf16* __restrict__ Kf, __bf16* __restrict__ Vf)
{
    __shared__ __bf16 wtileT[64][72];   // [c][k]
    __shared__ __bf16 ot[64][72];       // [t][c]

    const int tid  = threadIdx.x;
    const int lane = tid & 63;
    const int w    = tid >> 6;
    const int g    = lane >> 4;
    const int n    = lane & 15;
    const int n32  = lane & 31;
    const int hi   = lane >> 5;

    const int row0 = blockIdx.x * 64;
    const int gi   = blockIdx.y;          // 0..1
    const int b_   = row0 >> 11;
    const int t0   = row0 & (SEQ - 1);
    const int kb64 = t0 >> 6;

    const float* hrow = hidden + (size_t)(row0 + w * 16 + n) * HD + 8 * g;
    f32x4 h0 = *(const f32x4*)(hrow);
    f32x4 h1 = *(const f32x4*)(hrow + 4);
    f32x4 h2 = *(const f32x4*)(hrow + 32);
    f32x4 h3 = *(const f32x4*)(hrow + 36);
    bf16x8 a0, a1;
    #pragma unroll
    for (int j = 0; j < 4; ++j) {
        a0[j]     = (__bf16)h0[j];
        a0[j + 4] = (__bf16)h1[j];
        a1[j]     = (__bf16)h2[j];
        a1[j + 4] = (__bf16)h3[j];
    }

    const int dr   = tid >> 2;        // 0..63 (W row = k)
    const int coff = (tid & 3) * 16;  // 16 consecutive cols

    for (int tt = 0; tt < 18; ++tt) {
        const int tile_id = gi * 18 + tt;      // 0..35
        const int proj    = tile_id / 12;
        const int head    = tile_id % 12;
        const int bh      = b_ * NH + head;
        const float* W    = proj == 0 ? Wq : (proj == 1 ? Wk : Wv);
        const float* bias = proj == 0 ? bq : (proj == 1 ? bk : bv);
        const float qs    = (proj == 0) ? 0.125f * LOG2E : 1.0f;

        const float* wr = W + (size_t)dr * NP + head * 64 + coff;
        f32x4 x0 = *(const f32x4*)(wr);
        f32x4 x1 = *(const f32x4*)(wr + 4);
        f32x4 x2 = *(const f32x4*)(wr + 8);
        f32x4 x3 = *(const f32x4*)(wr + 12);
        #pragma unroll
        for (int i = 0; i < 4; ++i) {
            wtileT[coff + i     ][dr] = (__bf16)(x0[i] * qs);
            wtileT[coff + 4 + i ][dr] = (__bf16)(x1[i] * qs);
            wtileT[coff + 8 + i ][dr] = (__bf16)(x2[i] * qs);
            wtileT[coff + 12 + i][dr] = (__bf16)(x3[i] * qs);
        }
        __syncthreads();   // wtileT ready; also fences prev tile's ot reads

        #pragma unroll
        for (int dt = 0; dt < 4; ++dt) {
            const bf16x8 b0 = *(const bf16x8*)&wtileT[dt * 16 + n][8 * g];
            const bf16x8 b1 = *(const bf16x8*)&wtileT[dt * 16 + n][32 + 8 * g];
            f32x4 acc = {0.f, 0.f, 0.f, 0.f};
            acc = __builtin_amdgcn_mfma_f32_16x16x32_bf16(a0, b0, acc, 0, 0, 0);
            acc = __builtin_amdgcn_mfma_f32_16x16x32_bf16(a1, b1, acc, 0, 0, 0);
            const float bb = bias[head * 64 + dt * 16 + n] * qs;
            #pragma unroll
            for (int r = 0; r < 4; ++r)
                ot[w * 16 + 4 * g + r][dt * 16 + n] = (__bf16)(acc[r] + bb);
        }
        __syncthreads();   // ot complete; wtileT frag reads done

        if (proj == 0) {
            __bf16* dst = Qw + ((size_t)bh * SEQ + t0 + w * 16) * HD;
            const int tr = lane >> 2;
            const int d0 = (lane & 3) * 16;
            *(bf16x8*)(dst + (size_t)tr * HD + d0)     = *(const bf16x8*)&ot[w * 16 + tr][d0];
            *(bf16x8*)(dst + (size_t)tr * HD + d0 + 8) = *(const bf16x8*)&ot[w * 16 + tr][d0 + 8];
        } else if (proj == 1) {
            __bf16* base = Kf + (size_t)bh * SEQ * HD + (size_t)kb64 * 4096;
            #pragma unroll
            for (int sub = 0; sub < 2; ++sub) {
                const bf16x8 fr = *(const bf16x8*)&ot[sub * 32 + n32][w * 16 + 8 * hi];
                *(bf16x8*)(base + (size_t)(w * 2 + sub) * 512 + lane * 8) = fr;
            }
        } else {
            __bf16* base = Vf + (size_t)bh * SEQ * HD + (size_t)kb64 * 4096;
            #pragma unroll
            for (int dsub = 0; dsub < 2; ++dsub) {
                bf16x8 v;
                #pragma unroll
                for (int j = 0; j < 8; ++j)
                    v[j] = ot[w * 16 + ((j & 3) + 8 * (j >> 2) + 4 * hi)][dsub * 32 + n32];
                *(bf16x8*)(base + (size_t)(w * 2 + dsub) * 512 + lane * 8) = v;
            }
        }
    }
}

// ---------------------------------------------------------------------------
// Kernel 2 v13: v11's key-split flash body (K-prefetch reverted: measured
// neutral) + LDS shrunk to 35,328 B by UNIONING mdd (loop phase) with et
// (epilogue phase): 4 x 36KB granules = 144KB -> 4 resident blocks/CU.
// ---------------------------------------------------------------------------
__global__ __launch_bounds__(256, 4) void flash_attn_kernel(
    const __bf16* __restrict__ Qw, const __bf16* __restrict__ Kf,
    const __bf16* __restrict__ Vf, const float* __restrict__ amask,
    float* __restrict__ out)
{
    __shared__ __align__(16) char smem[35328];
    __bf16* mdd = (__bf16*)smem;                      // loop phase (4 KB)
    float (*et)[32][68] = (float(*)[32][68])smem;     // epilogue (34,816 B)
    float* lrow = (float*)(smem + 34816);             // epilogue (512 B)

    const int tid  = threadIdx.x;
    const int lane = tid & 63;
    const int w    = tid >> 6;
    const int n32  = lane & 31;
    const int hi   = lane >> 5;

    const int bid    = blockIdx.x;        // 3072
    const int xcd    = bid & 7;
    const int slot   = bid >> 3;          // 0..383
    const int bh     = xcd * 6 + (slot >> 6);
    const int qchunk = slot & 63;
    const int b_     = bh / NH;
    const int h      = bh % NH;
    const int q0     = qchunk * 32;

    // per-wave mdd slice (wave w reads exactly the slice it writes)
    const float* mp = amask + (size_t)b_ * SEQ;
    #pragma unroll
    for (int i = 0; i < 8; ++i) {
        const int idx = w * 512 + i * 64 + lane;
        mdd[idx] = (__bf16)fmaf(mp[idx], MASK_L2, -MASK_L2);
    }

    // Q as B-operand: B[k=16*dstep+8*hi+j][q=n32]
    const __bf16* Qrow = Qw + ((size_t)bh * SEQ + q0 + n32) * HD + 8 * hi;
    bf16x8 qf[4];
    #pragma unroll
    for (int d = 0; d < 4; ++d) qf[d] = load_bf16x8(Qrow + d * 16);

    bf16x8 qone;
    #pragma unroll
    for (int j = 0; j < 8; ++j) qone[j] = (__bf16)0.0f;
    if (hi == 0) qone[0] = (__bf16)1.0f;   // B[k=0][q] = 1

    const __bf16* kfb_ = Kf + (size_t)bh * SEQ * HD + (size_t)lane * 8;
    const __bf16* vfb_ = Vf + (size_t)bh * SEQ * HD + (size_t)lane * 8;

    f32x16 o0 = {0,0,0,0,0,0,0,0,0,0,0,0,0,0,0,0};
    f32x16 o1 = {0,0,0,0,0,0,0,0,0,0,0,0,0,0,0,0};
    f32x2 lsl2 = {0.f, 0.f};

    const int kstart = w * 512;
    for (int it = 0; it < 8; ++it) {
        const int kb = kstart + it * 64;
        const size_t foff = (size_t)(kb >> 6) * 4096;

        bf16x8 kfa[4], kfb[4], vf0[4], vf1[4];
        #pragma unroll
        for (int d = 0; d < 4; ++d) {
            kfa[d] = load_bf16x8(kfb_ + foff + (size_t)(2 * d) * 512);
            kfb[d] = load_bf16x8(kfb_ + foff + (size_t)(2 * d + 1) * 512);
        }
        #pragma unroll
        for (int c = 0; c < 4; ++c) {
            vf0[c] = load_bf16x8(vfb_ + foff + (size_t)(2 * c) * 512);
            vf1[c] = load_bf16x8(vfb_ + foff + (size_t)(2 * c + 1) * 512);
        }

        bf16x8 maa, mab;
        #pragma unroll
        for (int j = 0; j < 8; ++j) { maa[j] = (__bf16)0.0f; mab[j] = (__bf16)0.0f; }
        maa[0] = mdd[kb + n32];
        mab[0] = mdd[kb + 32 + n32];

        // ---- half 0: keys kb..kb+31 ----
        f32x16 sa = {0,0,0,0,0,0,0,0,0,0,0,0,0,0,0,0};
        #pragma unroll
        for (int d = 0; d < 4; ++d)
            sa = __builtin_amdgcn_mfma_f32_32x32x16_bf16(kfa[d], qf[d], sa, 0, 0, 0);
        sa = __builtin_amdgcn_mfma_f32_32x32x16_bf16(maa, qone, sa, 0, 0, 0);

        bf16x8 P0, P1;
        {
            float p[16];
            #pragma unroll
            for (int r = 0; r < 16; ++r) p[r] = hw_exp2(sa[r]);
            u32x4 B0, B1;
            #pragma unroll
            for (int i = 0; i < 4; ++i) {
                B0[i] = cvtpk2(p[2 * i],     p[2 * i + 1]);
                B1[i] = cvtpk2(p[8 + 2 * i], p[8 + 2 * i + 1]);
            }
            #pragma unroll
            for (int i = 0; i < 8; ++i) {
                f32x2 t; t[0] = p[2 * i]; t[1] = p[2 * i + 1];
                lsl2 += t;
            }
            P0 = __builtin_bit_cast(bf16x8, B0);
            P1 = __builtin_bit_cast(bf16x8, B1);
        }
        o0 = __builtin_amdgcn_mfma_f32_32x32x16_bf16(vf0[0], P0, o0, 0, 0, 0);
        o1 = __builtin_amdgcn_mfma_f32_32x32x16_bf16(vf1[0], P0, o1, 0, 0, 0);
        o0 = __builtin_amdgcn_mfma_f32_32x32x16_bf16(vf0[1], P1, o0, 0, 0, 0);
        o1 = __builtin_amdgcn_mfma_f32_32x32x16_bf16(vf1[1], P1, o1, 0, 0, 0);

        // ---- half 1: keys kb+32..kb+63 ----
        f32x16 sb = {0,0,0,0,0,0,0,0,0,0,0,0,0,0,0,0};
        #pragma unroll
        for (int d = 0; d < 4; ++d)
            sb = __builtin_amdgcn_mfma_f32_32x32x16_bf16(kfb[d], qf[d], sb, 0, 0, 0);
        sb = __builtin_amdgcn_mfma_f32_32x32x16_bf16(mab, qone, sb, 0, 0, 0);

        bf16x8 P2, P3;
        {
            float p[16];
            #pragma unroll
            for (int r = 0; r < 16; ++r) p[r] = hw_exp2(sb[r]);
            u32x4 B0, B1;
            #pragma unroll
            for (int i = 0; i < 4; ++i) {
                B0[i] = cvtpk2(p[2 * i],     p[2 * i + 1]);
                B1[i] = cvtpk2(p[8 + 2 * i], p[8 + 2 * i + 1]);
            }
            #pragma unroll
            for (int i = 0; i < 8; ++i) {
                f32x2 t; t[0] = p[2 * i]; t[1] = p[2 * i + 1];
                lsl2 += t;
            }
            P2 = __builtin_bit_cast(bf16x8, B0);
            P3 = __builtin_bit_cast(bf16x8, B1);
        }
        o0 = __builtin_amdgcn_mfma_f32_32x32x16_bf16(vf0[2], P2, o0, 0, 0, 0);
        o1 = __builtin_amdgcn_mfma_f32_32x32x16_bf16(vf1[2], P2, o1, 0, 0, 0);
        o0 = __builtin_amdgcn_mfma_f32_32x32x16_bf16(vf0[3], P3, o0, 0, 0, 0);
        o1 = __builtin_amdgcn_mfma_f32_32x32x16_bf16(vf1[3], P3, o1, 0, 0, 0);
    }

    // per-wave partial row sums: q=n32 lives on lanes n32 and n32+32
    float rs = lsl2[0] + lsl2[1];
    rs += __shfl_xor(rs, 32);

    __syncthreads();   // all waves past loop: mdd dead, safe to alias as et

    #pragma unroll
    for (int r = 0; r < 16; ++r) {
        const int dl = (r & 3) + 8 * (r >> 2) + 4 * hi;
        et[w][n32][dl]      = o0[r];
        et[w][n32][32 + dl] = o1[r];
    }
    if (lane < 32) lrow[w * 32 + n32] = rs;
    __syncthreads();

    const int q  = tid >> 3;
    const int d0 = (tid & 7) * 8;
    const float linv = 1.0f / (lrow[q] + lrow[32 + q] + lrow[64 + q] + lrow[96 + q]);
    f32x4 acc0 = {0,0,0,0}, acc1 = {0,0,0,0};
    #pragma unroll
    for (int ww = 0; ww < 4; ++ww) {
        acc0 += *(const f32x4*)&et[ww][q][d0];
        acc1 += *(const f32x4*)&et[ww][q][d0 + 4];
    }
    float* orow = out + ((size_t)(b_ * SEQ + q0 + q)) * NP + h * HD + d0;
    f32x4 r0, r1;
    #pragma unroll
    for (int i = 0; i < 4; ++i) { r0[i] = acc0[i] * linv; r1[i] = acc1[i] * linv; }
    *(f32x4*)(orow)     = r0;
    *(f32x4*)(orow + 4) = r1;
}

extern "C" void kernel_launch(void* const* d_in, const int* in_sizes, int n_in,
                              void* d_out, int out_size, void* d_ws, size_t ws_size,
                              hipStream_t stream) {
    const float* hidden = (const float*)d_in[0];
    const float* amask  = (const float*)d_in[1];
    const float* Wq     = (const float*)d_in[2];
    const float* bq     = (const float*)d_in[3];
    const float* Wk     = (const float*)d_in[4];
    const float* bk     = (const float*)d_in[5];
    const float* Wv     = (const float*)d_in[6];
    const float* bv     = (const float*)d_in[7];
    float* out = (float*)d_out;

    const size_t elems = (size_t)NB * NH * SEQ * HD; // 6,291,456
    __bf16* Qw = (__bf16*)d_ws;
    __bf16* Kf = Qw + elems;
    __bf16* Vf = Kf + elems;

    qkv_kernel<<<dim3(128, 2), 256, 0, stream>>>(
        hidden, Wq, Wk, Wv, bq, bk, bv, Qw, Kf, Vf);

    flash_attn_kernel<<<dim3(3072), 256, 0, stream>>>(
        Qw, Kf, Vf, amask, out);
}

// Round 15
// 174.061 us; speedup vs baseline: 1.0209x; 1.0209x over previous
//
#include <hip/hip_runtime.h>
#include <hip/hip_bf16.h>

#define NH 12
#define HD 64
#define NB 4
#define SEQ 2048
#define NP 768
#define LOG2E 1.44269504f
#define MASK_L2 14426.9504f   // 10000 * log2(e)

typedef __bf16 bf16x8 __attribute__((ext_vector_type(8)));
typedef __bf16 bf16x2 __attribute__((ext_vector_type(2)));
typedef float f32x2 __attribute__((ext_vector_type(2)));
typedef float f32x4 __attribute__((ext_vector_type(4)));
typedef float f32x16 __attribute__((ext_vector_type(16)));
typedef unsigned u32x4 __attribute__((ext_vector_type(4)));

static __device__ __forceinline__ bf16x8 load_bf16x8(const __bf16* p) {
    return *reinterpret_cast<const bf16x8*>(p);
}
static __device__ __forceinline__ float hw_exp2(float x) {
    return __builtin_amdgcn_exp2f(x);
}
// packed f32x2 -> bf16x2 (backend can select v_cvt_pk_bf16_f32 on gfx950)
static __device__ __forceinline__ unsigned cvtpk2(float lo, float hi) {
    f32x2 t; t[0] = lo; t[1] = hi;
    return __builtin_bit_cast(unsigned, __builtin_convertvector(t, bf16x2));
}

// ---------------------------------------------------------------------------
// Kernel 0 (verified round 5): W (64,768) fp32 -> Wt (768,64) bf16,
// 0.125*log2e folded for Q. grid (12,3).
// ---------------------------------------------------------------------------
__global__ __launch_bounds__(256) void wt_kernel(
    const float* __restrict__ Wq, const float* __restrict__ Wk,
    const float* __restrict__ Wv, __bf16* __restrict__ Wt)
{
    __shared__ float tile[64][69];
    const int by = blockIdx.y;
    const float* W = by == 0 ? Wq : (by == 1 ? Wk : Wv);
    const float scale = (by == 0) ? 0.125f * LOG2E : 1.0f;
    const int p0 = blockIdx.x * 64;
    const int tl = threadIdx.x & 63;
    const int tq = threadIdx.x >> 6;
    #pragma unroll
    for (int i = 0; i < 16; ++i) {
        const int d = tq + 4 * i;
        tile[tl][d] = W[(size_t)d * NP + p0 + tl];
    }
    __syncthreads();
    #pragma unroll
    for (int i = 0; i < 16; ++i) {
        const int pl = tq + 4 * i;
        Wt[((size_t)by * NP + p0 + pl) * HD + tl] = (__bf16)(tile[pl][tl] * scale);
    }
}

// ---------------------------------------------------------------------------
// Kernel 1 v14: QKV projection, BARRIER-FREE for Q and V blocks.
// grid (128, 6); block = 64 t-rows; tiles gi*6..gi*6+5 so gi 0-1 = Q,
// gi 2-3 = K, gi 4-5 = V. B-fragments load contiguous 16B from precomputed
// Wt (no LDS W stage). Q-stores and sigma-permuted V-stores read only the
// wave's OWN 16 ot rows (same-wave RAW -> no barrier). Only K blocks need
// the cross-wave key gather -> 2 barriers/tile there. LDS = 9.2 KB.
// ---------------------------------------------------------------------------
__global__ __launch_bounds__(256) void qkv_kernel(
    const float* __restrict__ hidden, const __bf16* __restrict__ Wt,
    const float* __restrict__ bq, const float* __restrict__ bk,
    const float* __restrict__ bv,
    __bf16* __restrict__ Qw, __bf16* __restrict__ Kf, __bf16* __restrict__ Vf)
{
    __shared__ __bf16 ot[64][72];       // [t-local][c]

    const int tid  = threadIdx.x;
    const int lane = tid & 63;
    const int w    = tid >> 6;
    const int g    = lane >> 4;
    const int n    = lane & 15;
    const int n32  = lane & 31;
    const int hi   = lane >> 5;

    const int row0 = blockIdx.x * 64;
    const int gi   = blockIdx.y;          // 0..5
    const int b_   = row0 >> 11;
    const int t0   = row0 & (SEQ - 1);
    const int kb64 = t0 >> 6;

    const float* hrow = hidden + (size_t)(row0 + w * 16 + n) * HD + 8 * g;
    f32x4 h0 = *(const f32x4*)(hrow);
    f32x4 h1 = *(const f32x4*)(hrow + 4);
    f32x4 h2 = *(const f32x4*)(hrow + 32);
    f32x4 h3 = *(const f32x4*)(hrow + 36);
    bf16x8 a0, a1;
    #pragma unroll
    for (int j = 0; j < 4; ++j) {
        a0[j]     = (__bf16)h0[j];
        a0[j + 4] = (__bf16)h1[j];
        a1[j]     = (__bf16)h2[j];
        a1[j + 4] = (__bf16)h3[j];
    }

    for (int tt = 0; tt < 6; ++tt) {
        const int tile_id = gi * 6 + tt;       // 0..35
        const int proj    = tile_id / 12;
        const int head    = tile_id % 12;
        const int bh      = b_ * NH + head;
        const float* bias = proj == 0 ? bq : (proj == 1 ? bk : bv);
        const float qs    = (proj == 0) ? 0.125f * LOG2E : 1.0f;

        // B-frags: contiguous 16B from Wt (scale already folded for Q)
        #pragma unroll
        for (int dt = 0; dt < 4; ++dt) {
            const __bf16* wp = Wt +
                ((size_t)proj * NP + head * 64 + dt * 16 + n) * HD + 8 * g;
            const bf16x8 b0 = load_bf16x8(wp);
            const bf16x8 b1 = load_bf16x8(wp + 32);
            f32x4 acc = {0.f, 0.f, 0.f, 0.f};
            acc = __builtin_amdgcn_mfma_f32_16x16x32_bf16(a0, b0, acc, 0, 0, 0);
            acc = __builtin_amdgcn_mfma_f32_16x16x32_bf16(a1, b1, acc, 0, 0, 0);
            const float bb = bias[head * 64 + dt * 16 + n] * qs;
            #pragma unroll
            for (int r = 0; r < 4; ++r)
                ot[w * 16 + 4 * g + r][dt * 16 + n] = (__bf16)(acc[r] + bb);
        }

        if (proj == 0) {
            // own-wave rows only: no barrier
            __bf16* dst = Qw + ((size_t)bh * SEQ + t0 + w * 16) * HD;
            const int tr = lane >> 2;
            const int d0 = (lane & 3) * 16;
            *(bf16x8*)(dst + (size_t)tr * HD + d0)     = *(const bf16x8*)&ot[w * 16 + tr][d0];
            *(bf16x8*)(dst + (size_t)tr * HD + d0 + 8) = *(const bf16x8*)&ot[w * 16 + tr][d0 + 8];
        } else if (proj == 1) {
            // cross-wave key gather: needs barriers
            __syncthreads();
            __bf16* base = Kf + (size_t)bh * SEQ * HD + (size_t)kb64 * 4096;
            #pragma unroll
            for (int sub = 0; sub < 2; ++sub) {
                const bf16x8 fr = *(const bf16x8*)&ot[sub * 32 + n32][w * 16 + 8 * hi];
                *(bf16x8*)(base + (size_t)(w * 2 + sub) * 512 + lane * 8) = fr;
            }
            __syncthreads();
        } else {
            // sigma rows (j&3)+8*(j>>2)+4*hi in [0,16): own-wave, no barrier
            __bf16* base = Vf + (size_t)bh * SEQ * HD + (size_t)kb64 * 4096;
            #pragma unroll
            for (int dsub = 0; dsub < 2; ++dsub) {
                bf16x8 v;
                #pragma unroll
                for (int j = 0; j < 8; ++j)
                    v[j] = ot[w * 16 + ((j & 3) + 8 * (j >> 2) + 4 * hi)][dsub * 32 + n32];
                *(bf16x8*)(base + (size_t)(w * 2 + dsub) * 512 + lane * 8) = v;
            }
        }
    }
}

// ---------------------------------------------------------------------------
// Kernel 2 (byte-identical to v13, 78.0 us): key-split flash, zero cross-lane
// ops in the loop, mdd/et LDS union.
// ---------------------------------------------------------------------------
__global__ __launch_bounds__(256, 4) void flash_attn_kernel(
    const __bf16* __restrict__ Qw, const __bf16* __restrict__ Kf,
    const __bf16* __restrict__ Vf, const float* __restrict__ amask,
    float* __restrict__ out)
{
    __shared__ __align__(16) char smem[35328];
    __bf16* mdd = (__bf16*)smem;                      // loop phase (4 KB)
    float (*et)[32][68] = (float(*)[32][68])smem;     // epilogue (34,816 B)
    float* lrow = (float*)(smem + 34816);             // epilogue (512 B)

    const int tid  = threadIdx.x;
    const int lane = tid & 63;
    const int w    = tid >> 6;
    const int n32  = lane & 31;
    const int hi   = lane >> 5;

    const int bid    = blockIdx.x;        // 3072
    const int xcd    = bid & 7;
    const int slot   = bid >> 3;          // 0..383
    const int bh     = xcd * 6 + (slot >> 6);
    const int qchunk = slot & 63;
    const int b_     = bh / NH;
    const int h      = bh % NH;
    const int q0     = qchunk * 32;

    const float* mp = amask + (size_t)b_ * SEQ;
    #pragma unroll
    for (int i = 0; i < 8; ++i) {
        const int idx = w * 512 + i * 64 + lane;
        mdd[idx] = (__bf16)fmaf(mp[idx], MASK_L2, -MASK_L2);
    }

    const __bf16* Qrow = Qw + ((size_t)bh * SEQ + q0 + n32) * HD + 8 * hi;
    bf16x8 qf[4];
    #pragma unroll
    for (int d = 0; d < 4; ++d) qf[d] = load_bf16x8(Qrow + d * 16);

    bf16x8 qone;
    #pragma unroll
    for (int j = 0; j < 8; ++j) qone[j] = (__bf16)0.0f;
    if (hi == 0) qone[0] = (__bf16)1.0f;   // B[k=0][q] = 1

    const __bf16* kfb_ = Kf + (size_t)bh * SEQ * HD + (size_t)lane * 8;
    const __bf16* vfb_ = Vf + (size_t)bh * SEQ * HD + (size_t)lane * 8;

    f32x16 o0 = {0,0,0,0,0,0,0,0,0,0,0,0,0,0,0,0};
    f32x16 o1 = {0,0,0,0,0,0,0,0,0,0,0,0,0,0,0,0};
    f32x2 lsl2 = {0.f, 0.f};

    const int kstart = w * 512;
    for (int it = 0; it < 8; ++it) {
        const int kb = kstart + it * 64;
        const size_t foff = (size_t)(kb >> 6) * 4096;

        bf16x8 kfa[4], kfb[4], vf0[4], vf1[4];
        #pragma unroll
        for (int d = 0; d < 4; ++d) {
            kfa[d] = load_bf16x8(kfb_ + foff + (size_t)(2 * d) * 512);
            kfb[d] = load_bf16x8(kfb_ + foff + (size_t)(2 * d + 1) * 512);
        }
        #pragma unroll
        for (int c = 0; c < 4; ++c) {
            vf0[c] = load_bf16x8(vfb_ + foff + (size_t)(2 * c) * 512);
            vf1[c] = load_bf16x8(vfb_ + foff + (size_t)(2 * c + 1) * 512);
        }

        bf16x8 maa, mab;
        #pragma unroll
        for (int j = 0; j < 8; ++j) { maa[j] = (__bf16)0.0f; mab[j] = (__bf16)0.0f; }
        maa[0] = mdd[kb + n32];
        mab[0] = mdd[kb + 32 + n32];

        // ---- half 0 ----
        f32x16 sa = {0,0,0,0,0,0,0,0,0,0,0,0,0,0,0,0};
        #pragma unroll
        for (int d = 0; d < 4; ++d)
            sa = __builtin_amdgcn_mfma_f32_32x32x16_bf16(kfa[d], qf[d], sa, 0, 0, 0);
        sa = __builtin_amdgcn_mfma_f32_32x32x16_bf16(maa, qone, sa, 0, 0, 0);

        bf16x8 P0, P1;
        {
            float p[16];
            #pragma unroll
            for (int r = 0; r < 16; ++r) p[r] = hw_exp2(sa[r]);
            u32x4 B0, B1;
            #pragma unroll
            for (int i = 0; i < 4; ++i) {
                B0[i] = cvtpk2(p[2 * i],     p[2 * i + 1]);
                B1[i] = cvtpk2(p[8 + 2 * i], p[8 + 2 * i + 1]);
            }
            #pragma unroll
            for (int i = 0; i < 8; ++i) {
                f32x2 t; t[0] = p[2 * i]; t[1] = p[2 * i + 1];
                lsl2 += t;
            }
            P0 = __builtin_bit_cast(bf16x8, B0);
            P1 = __builtin_bit_cast(bf16x8, B1);
        }
        o0 = __builtin_amdgcn_mfma_f32_32x32x16_bf16(vf0[0], P0, o0, 0, 0, 0);
        o1 = __builtin_amdgcn_mfma_f32_32x32x16_bf16(vf1[0], P0, o1, 0, 0, 0);
        o0 = __builtin_amdgcn_mfma_f32_32x32x16_bf16(vf0[1], P1, o0, 0, 0, 0);
        o1 = __builtin_amdgcn_mfma_f32_32x32x16_bf16(vf1[1], P1, o1, 0, 0, 0);

        // ---- half 1 ----
        f32x16 sb = {0,0,0,0,0,0,0,0,0,0,0,0,0,0,0,0};
        #pragma unroll
        for (int d = 0; d < 4; ++d)
            sb = __builtin_amdgcn_mfma_f32_32x32x16_bf16(kfb[d], qf[d], sb, 0, 0, 0);
        sb = __builtin_amdgcn_mfma_f32_32x32x16_bf16(mab, qone, sb, 0, 0, 0);

        bf16x8 P2, P3;
        {
            float p[16];
            #pragma unroll
            for (int r = 0; r < 16; ++r) p[r] = hw_exp2(sb[r]);
            u32x4 B0, B1;
            #pragma unroll
            for (int i = 0; i < 4; ++i) {
                B0[i] = cvtpk2(p[2 * i],     p[2 * i + 1]);
                B1[i] = cvtpk2(p[8 + 2 * i], p[8 + 2 * i + 1]);
            }
            #pragma unroll
            for (int i = 0; i < 8; ++i) {
                f32x2 t; t[0] = p[2 * i]; t[1] = p[2 * i + 1];
                lsl2 += t;
            }
            P2 = __builtin_bit_cast(bf16x8, B0);
            P3 = __builtin_bit_cast(bf16x8, B1);
        }
        o0 = __builtin_amdgcn_mfma_f32_32x32x16_bf16(vf0[2], P2, o0, 0, 0, 0);
        o1 = __builtin_amdgcn_mfma_f32_32x32x16_bf16(vf1[2], P2, o1, 0, 0, 0);
        o0 = __builtin_amdgcn_mfma_f32_32x32x16_bf16(vf0[3], P3, o0, 0, 0, 0);
        o1 = __builtin_amdgcn_mfma_f32_32x32x16_bf16(vf1[3], P3, o1, 0, 0, 0);
    }

    float rs = lsl2[0] + lsl2[1];
    rs += __shfl_xor(rs, 32);

    __syncthreads();   // all waves past loop: mdd dead, safe to alias as et

    #pragma unroll
    for (int r = 0; r < 16; ++r) {
        const int dl = (r & 3) + 8 * (r >> 2) + 4 * hi;
        et[w][n32][dl]      = o0[r];
        et[w][n32][32 + dl] = o1[r];
    }
    if (lane < 32) lrow[w * 32 + n32] = rs;
    __syncthreads();

    const int q  = tid >> 3;
    const int d0 = (tid & 7) * 8;
    const float linv = 1.0f / (lrow[q] + lrow[32 + q] + lrow[64 + q] + lrow[96 + q]);
    f32x4 acc0 = {0,0,0,0}, acc1 = {0,0,0,0};
    #pragma unroll
    for (int ww = 0; ww < 4; ++ww) {
        acc0 += *(const f32x4*)&et[ww][q][d0];
        acc1 += *(const f32x4*)&et[ww][q][d0 + 4];
    }
    float* orow = out + ((size_t)(b_ * SEQ + q0 + q)) * NP + h * HD + d0;
    f32x4 r0, r1;
    #pragma unroll
    for (int i = 0; i < 4; ++i) { r0[i] = acc0[i] * linv; r1[i] = acc1[i] * linv; }
    *(f32x4*)(orow)     = r0;
    *(f32x4*)(orow + 4) = r1;
}

extern "C" void kernel_launch(void* const* d_in, const int* in_sizes, int n_in,
                              void* d_out, int out_size, void* d_ws, size_t ws_size,
                              hipStream_t stream) {
    const float* hidden = (const float*)d_in[0];
    const float* amask  = (const float*)d_in[1];
    const float* Wq     = (const float*)d_in[2];
    const float* bq     = (const float*)d_in[3];
    const float* Wk     = (const float*)d_in[4];
    const float* bk     = (const float*)d_in[5];
    const float* Wv     = (const float*)d_in[6];
    const float* bv     = (const float*)d_in[7];
    float* out = (float*)d_out;

    const size_t elems = (size_t)NB * NH * SEQ * HD; // 6,291,456
    __bf16* Qw = (__bf16*)d_ws;
    __bf16* Kf = Qw + elems;
    __bf16* Vf = Kf + elems;
    __bf16* Wt = Vf + elems;    // 3*768*64 bf16 = 294 KB

    wt_kernel<<<dim3(12, 3), 256, 0, stream>>>(Wq, Wk, Wv, Wt);

    qkv_kernel<<<dim3(128, 6), 256, 0, stream>>>(
        hidden, Wt, bq, bk, bv, Qw, Kf, Vf);

    flash_attn_kernel<<<dim3(3072), 256, 0, stream>>>(
        Qw, Kf, Vf, amask, out);
}